// Round 1
// baseline (5661.853 us; speedup 1.0000x reference)
//
#include <hip/hip_runtime.h>

// GCN: out = A_norm @ relu(A_norm @ (x@W1) + b1) @ W2 ... precisely:
//   t1 = x@W1 ; h = relu(seg_sum(norm * t1[src] -> dst) + b1)
//   t2 = h@W2 ; out = seg_sum(norm * t2[src] -> dst) + b2
// with self-loops appended (src=dst=i, norm=dinv[i]^2).

// ---------------- degree / norm ----------------
__global__ void k_deg_init(int* deg, int n) {
    int i = blockIdx.x * 256 + threadIdx.x;
    if (i < n) deg[i] = 1;  // self-loop
}

__global__ void k_deg_edges(const int* __restrict__ dst, int* deg, int e) {
    int i = blockIdx.x * 256 + threadIdx.x;
    if (i < e) atomicAdd(&deg[dst[i]], 1);
}

__global__ void k_rsqrt(const int* __restrict__ degi, float* dinv, int n) {
    int i = blockIdx.x * 256 + threadIdx.x;
    if (i < n) {
        float d = (float)degi[i];
        dinv[i] = rsqrtf(d);   // deg >= 1 always (self-loop)
    }
}

// ---------------- GEMM: out[N x 128] = (relu?)(in[N x 128]) @ W[128 x 128] ----------------
// Block: 256 threads, 32 rows per block. W staged in LDS in two 64-k-row halves
// (48 KB total LDS -> 3 blocks/CU). 4 rows x 4 cols per thread, float4 LDS reads.
__global__ __launch_bounds__(256, 2) void k_gemm(const float* __restrict__ in,
                                                 const float* __restrict__ W,
                                                 float* __restrict__ out,
                                                 int nrows_total, int relu_in) {
    __shared__ float Wl[64 * 128];  // 32 KB (half of W's k-rows)
    __shared__ float Xl[32 * 128];  // 16 KB
    const int t = threadIdx.x;
    const long long row0 = (long long)blockIdx.x * 32;
    int nr = nrows_total - (int)row0;
    if (nr > 32) nr = 32;

    // stage X tile (apply relu on the fly for layer 2)
    for (int i = t * 4; i < nr * 128; i += 256 * 4) {
        float4 v = *(const float4*)&in[row0 * 128 + i];
        if (relu_in) {
            v.x = fmaxf(v.x, 0.f); v.y = fmaxf(v.y, 0.f);
            v.z = fmaxf(v.z, 0.f); v.w = fmaxf(v.w, 0.f);
        }
        *(float4*)&Xl[i] = v;
    }

    const int c4 = t & 31;   // output col group: cols 4*c4 .. 4*c4+3
    const int rg = t >> 5;   // row group 0..7 -> rows rg + 8r
    float4 acc[4];
#pragma unroll
    for (int r = 0; r < 4; r++) acc[r] = make_float4(0.f, 0.f, 0.f, 0.f);

    for (int half = 0; half < 2; half++) {
        __syncthreads();  // X ready (iter 0) / previous Wl fully consumed (iter 1)
        // stage 64 k-rows of W
        for (int i = t * 4; i < 64 * 128; i += 256 * 4)
            *(float4*)&Wl[i] = *(const float4*)&W[half * 64 * 128 + i];
        __syncthreads();
#pragma unroll 4
        for (int k4 = 0; k4 < 16; k4++) {
            float4 wv0 = *(float4*)&Wl[(k4 * 4 + 0) * 128 + c4 * 4];
            float4 wv1 = *(float4*)&Wl[(k4 * 4 + 1) * 128 + c4 * 4];
            float4 wv2 = *(float4*)&Wl[(k4 * 4 + 2) * 128 + c4 * 4];
            float4 wv3 = *(float4*)&Wl[(k4 * 4 + 3) * 128 + c4 * 4];
#pragma unroll
            for (int r = 0; r < 4; r++) {
                float4 xv = *(float4*)&Xl[(rg + r * 8) * 128 + half * 64 + k4 * 4];
                acc[r].x += xv.x * wv0.x + xv.y * wv1.x + xv.z * wv2.x + xv.w * wv3.x;
                acc[r].y += xv.x * wv0.y + xv.y * wv1.y + xv.z * wv2.y + xv.w * wv3.y;
                acc[r].z += xv.x * wv0.z + xv.y * wv1.z + xv.z * wv2.z + xv.w * wv3.z;
                acc[r].w += xv.x * wv0.w + xv.y * wv1.w + xv.z * wv2.w + xv.w * wv3.w;
            }
        }
    }

#pragma unroll
    for (int r = 0; r < 4; r++) {
        int rr = rg + r * 8;
        if (rr < nr) *(float4*)&out[(row0 + rr) * 128 + c4 * 4] = acc[r];
    }
}

// ---------------- bias + self-loop init: buf[i][c] = bias[c] + dinv[i]^2 * t[i][c] ----------------
__global__ void k_init_self(float* __restrict__ outb, const float* __restrict__ t,
                            const float* __restrict__ dinv, const float* __restrict__ bias,
                            int n) {
    long long i4 = (long long)blockIdx.x * 256 + threadIdx.x;  // over n*32 float4s
    if (i4 >= (long long)n * 32) return;
    int row = (int)(i4 >> 5);
    int c4 = (int)(i4 & 31);
    float dv = dinv[row];
    float d2 = dv * dv;
    float4 tv = *(const float4*)&t[i4 * 4];
    float4 bv = *(const float4*)&bias[c4 * 4];
    float4 o;
    o.x = bv.x + d2 * tv.x;
    o.y = bv.y + d2 * tv.y;
    o.z = bv.z + d2 * tv.z;
    o.w = bv.w + d2 * tv.w;
    *(float4*)&outb[i4 * 4] = o;
}

// ---------------- edge aggregation: out[dst] += dinv[src]*dinv[dst] * t[src] ----------------
// 32 lanes per edge, float4 gather, 4 scalar f32 HW atomics per lane.
__global__ void k_agg_edges(const int* __restrict__ src, const int* __restrict__ dst,
                            const float* __restrict__ dinv, const float* __restrict__ t,
                            float* __restrict__ out, int E) {
    long long gid = (long long)blockIdx.x * 256 + threadIdx.x;
    long long e = gid >> 5;
    if (e >= E) return;
    int lane = (int)(gid & 31);
    int s = src[e];
    int d = dst[e];
    float nrm = dinv[s] * dinv[d];
    float4 v = *(const float4*)&t[(long long)s * 128 + lane * 4];
    float* o = &out[(long long)d * 128 + lane * 4];
    unsafeAtomicAdd(o + 0, nrm * v.x);
    unsafeAtomicAdd(o + 1, nrm * v.y);
    unsafeAtomicAdd(o + 2, nrm * v.z);
    unsafeAtomicAdd(o + 3, nrm * v.w);
}

extern "C" void kernel_launch(void* const* d_in, const int* in_sizes, int n_in,
                              void* d_out, int out_size, void* d_ws, size_t ws_size,
                              hipStream_t stream) {
    const int N = in_sizes[0] / 128;
    const int E = in_sizes[1] / 2;
    const float* x  = (const float*)d_in[0];
    const int*   ei = (const int*)d_in[1];
    const float* W1 = (const float*)d_in[2];
    const float* b1 = (const float*)d_in[3];
    const float* W2 = (const float*)d_in[4];
    const float* b2 = (const float*)d_in[5];

    const int* src = ei;        // edge_index[0]
    const int* dst = ei + E;    // edge_index[1]

    float* dinv = (float*)d_ws;            // N floats (int deg during setup)
    float* t    = dinv + N;                 // N*128 floats (t1/t2 temp)
    float* h    = (float*)d_out;            // layer-1 hidden lives in d_out
    float* out  = (float*)d_out;

    const int nb_n  = (N + 255) / 256;
    const int nb_e  = (E + 255) / 256;
    const int nb_g  = (N + 31) / 32;
    const int nb_i  = (N * 32 + 255) / 256;
    const int nb_a  = (int)(((long long)E * 32 + 255) / 256);

    // degree + norm (cached, reused by both layers)
    k_deg_init<<<nb_n, 256, 0, stream>>>((int*)dinv, N);
    k_deg_edges<<<nb_e, 256, 0, stream>>>(dst, (int*)dinv, E);
    k_rsqrt<<<nb_n, 256, 0, stream>>>((const int*)dinv, dinv, N);

    // layer 1: t = x@W1 ; h = b1 + dinv^2*t + scatter(norm * t[src])
    k_gemm<<<nb_g, 256, 0, stream>>>(x, W1, t, N, 0);
    k_init_self<<<nb_i, 256, 0, stream>>>(h, t, dinv, b1, N);
    k_agg_edges<<<nb_a, 256, 0, stream>>>(src, dst, dinv, t, h, E);

    // layer 2: t = relu(h)@W2 ; out = b2 + dinv^2*t + scatter(norm * t[src])
    k_gemm<<<nb_g, 256, 0, stream>>>(h, W2, t, N, 1);
    k_init_self<<<nb_i, 256, 0, stream>>>(out, t, dinv, b2, N);
    k_agg_edges<<<nb_a, 256, 0, stream>>>(src, dst, dinv, t, out, E);
}

// Round 2
// 666.647 us; speedup vs baseline: 8.4930x; 8.4930x over previous
//
#include <hip/hip_runtime.h>

// Two-layer cached GCN. Round 2: replace 218M f32 atomics/layer with a
// per-call CSR build (histogram -> scan -> fill), then row-parallel
// gather-aggregate with register accumulation and one clean store per row.
//
//   deg[d]   = #edges into d            (self-loop added as +1)
//   dinv     = rsqrt(deg+1)
//   t = x@W1 ; h = b1 + dinv[d]^2*t[d] + sum_{(s,d)} dinv[s]dinv[d] t[s]
//   t = relu(h)@W2 ; out = same aggregation with b2

// ---------------- degree histogram ----------------
__global__ void k_deg_edges(const int* __restrict__ dst, int* __restrict__ deg, int e) {
    int i = blockIdx.x * 256 + threadIdx.x;
    if (i < e) atomicAdd(&deg[dst[i]], 1);
}

// ---------------- exclusive scan (3 kernels) + dinv ----------------
__global__ void k_scan1(const int* __restrict__ deg, float* __restrict__ dinv,
                        int* __restrict__ ofs, int* __restrict__ sums, int n) {
    __shared__ int sh[256];
    const int t = threadIdx.x;
    const int i = blockIdx.x * 256 + t;
    int v = (i < n) ? deg[i] : 0;
    if (i < n) dinv[i] = rsqrtf((float)v + 1.0f);  // +1 self-loop
    int x = v;
    sh[t] = x;
    __syncthreads();
    for (int o = 1; o < 256; o <<= 1) {
        int y = (t >= o) ? sh[t - o] : 0;
        __syncthreads();
        x += y;
        sh[t] = x;
        __syncthreads();
    }
    if (i < n) ofs[i] = x - v;              // exclusive within block
    if (t == 255) sums[blockIdx.x] = x;     // block total
}

__global__ void k_scan2(int* __restrict__ sums, int nb) {
    __shared__ int sh[512];
    const int t = threadIdx.x;
    int carry = 0;
    for (int base = 0; base < nb; base += 512) {
        int i = base + t;
        int v = (i < nb) ? sums[i] : 0;
        int x = v;
        sh[t] = x;
        __syncthreads();
        for (int o = 1; o < 512; o <<= 1) {
            int y = (t >= o) ? sh[t - o] : 0;
            __syncthreads();
            x += y;
            sh[t] = x;
            __syncthreads();
        }
        if (i < nb) sums[i] = x - v + carry;  // exclusive + carry
        int tot = sh[511];
        __syncthreads();
        carry += tot;
    }
}

__global__ void k_scan3(int* __restrict__ ofs, int* __restrict__ cursor,
                        const int* __restrict__ sums, int n, int E) {
    int i = blockIdx.x * 256 + threadIdx.x;
    if (i < n) {
        int v = ofs[i] + sums[blockIdx.x];
        ofs[i] = v;
        cursor[i] = v;
    }
    if (i == 0) ofs[n] = E;
}

// ---------------- CSR fill: col[pos] = src, grouped by dst ----------------
__global__ void k_fill(const int* __restrict__ src, const int* __restrict__ dst,
                       int* __restrict__ cursor, int* __restrict__ col, int E) {
    int e = blockIdx.x * 256 + threadIdx.x;
    if (e < E) {
        int d = dst[e];
        int pos = atomicAdd(&cursor[d], 1);
        col[pos] = src[e];
    }
}

// ---------------- GEMM: out[N x 128] = (relu?)(in[N x 128]) @ W[128 x 128] ----------------
__global__ __launch_bounds__(256, 2) void k_gemm(const float* __restrict__ in,
                                                 const float* __restrict__ W,
                                                 float* __restrict__ out,
                                                 int nrows_total, int relu_in) {
    __shared__ float Wl[64 * 128];  // 32 KB (half of W's k-rows)
    __shared__ float Xl[32 * 128];  // 16 KB
    const int t = threadIdx.x;
    const long long row0 = (long long)blockIdx.x * 32;
    int nr = nrows_total - (int)row0;
    if (nr > 32) nr = 32;

    for (int i = t * 4; i < nr * 128; i += 256 * 4) {
        float4 v = *(const float4*)&in[row0 * 128 + i];
        if (relu_in) {
            v.x = fmaxf(v.x, 0.f); v.y = fmaxf(v.y, 0.f);
            v.z = fmaxf(v.z, 0.f); v.w = fmaxf(v.w, 0.f);
        }
        *(float4*)&Xl[i] = v;
    }

    const int c4 = t & 31;
    const int rg = t >> 5;
    float4 acc[4];
#pragma unroll
    for (int r = 0; r < 4; r++) acc[r] = make_float4(0.f, 0.f, 0.f, 0.f);

    for (int half = 0; half < 2; half++) {
        __syncthreads();
        for (int i = t * 4; i < 64 * 128; i += 256 * 4)
            *(float4*)&Wl[i] = *(const float4*)&W[half * 64 * 128 + i];
        __syncthreads();
#pragma unroll 4
        for (int k4 = 0; k4 < 16; k4++) {
            float4 wv0 = *(float4*)&Wl[(k4 * 4 + 0) * 128 + c4 * 4];
            float4 wv1 = *(float4*)&Wl[(k4 * 4 + 1) * 128 + c4 * 4];
            float4 wv2 = *(float4*)&Wl[(k4 * 4 + 2) * 128 + c4 * 4];
            float4 wv3 = *(float4*)&Wl[(k4 * 4 + 3) * 128 + c4 * 4];
#pragma unroll
            for (int r = 0; r < 4; r++) {
                float4 xv = *(float4*)&Xl[(rg + r * 8) * 128 + half * 64 + k4 * 4];
                acc[r].x += xv.x * wv0.x + xv.y * wv1.x + xv.z * wv2.x + xv.w * wv3.x;
                acc[r].y += xv.x * wv0.y + xv.y * wv1.y + xv.z * wv2.y + xv.w * wv3.y;
                acc[r].z += xv.x * wv0.z + xv.y * wv1.z + xv.z * wv2.z + xv.w * wv3.z;
                acc[r].w += xv.x * wv0.w + xv.y * wv1.w + xv.z * wv2.w + xv.w * wv3.w;
            }
        }
    }

#pragma unroll
    for (int r = 0; r < 4; r++) {
        int rr = rg + r * 8;
        if (rr < nr) *(float4*)&out[(row0 + rr) * 128 + c4 * 4] = acc[r];
    }
}

// ---------------- CSR aggregation: one 32-lane group per dst row ----------------
// out[d] = bias + dinv[d]^2 * t[d] + sum_j dinv[col[j]]*dinv[d] * t[col[j]]
__global__ __launch_bounds__(256) void k_agg_csr(const int* __restrict__ ofs,
                                                 const int* __restrict__ col,
                                                 const float* __restrict__ dinv,
                                                 const float* __restrict__ t,
                                                 const float* __restrict__ bias,
                                                 float* __restrict__ out, int n) {
    int gid = blockIdx.x * 256 + threadIdx.x;
    int row = gid >> 5;
    int lane = gid & 31;
    if (row >= n) return;

    float dd = dinv[row];
    float d2 = dd * dd;
    int beg = ofs[row];
    int end = ofs[row + 1];

    float4 tv = *(const float4*)&t[(long long)row * 128 + lane * 4];
    float4 bv = *(const float4*)&bias[lane * 4];
    float4 acc;
    acc.x = bv.x + d2 * tv.x;
    acc.y = bv.y + d2 * tv.y;
    acc.z = bv.z + d2 * tv.z;
    acc.w = bv.w + d2 * tv.w;

    for (int j = beg; j < end; j++) {
        int s = col[j];                      // broadcast across the 32 lanes
        float nrm = dinv[s] * dd;
        float4 v = *(const float4*)&t[(long long)s * 128 + lane * 4];
        acc.x += nrm * v.x;
        acc.y += nrm * v.y;
        acc.z += nrm * v.z;
        acc.w += nrm * v.w;
    }
    *(float4*)&out[(long long)row * 128 + lane * 4] = acc;
}

extern "C" void kernel_launch(void* const* d_in, const int* in_sizes, int n_in,
                              void* d_out, int out_size, void* d_ws, size_t ws_size,
                              hipStream_t stream) {
    const int N = in_sizes[0] / 128;
    const int E = in_sizes[1] / 2;
    const float* x  = (const float*)d_in[0];
    const int*   ei = (const int*)d_in[1];
    const float* W1 = (const float*)d_in[2];
    const float* b1 = (const float*)d_in[3];
    const float* W2 = (const float*)d_in[4];
    const float* b2 = (const float*)d_in[5];

    const int* src = ei;
    const int* dst = ei + E;

    const int nb_n = (N + 255) / 256;   // 256-blocks over nodes

    // workspace layout (all 4-byte elems; t first for 16B alignment)
    float* t      = (float*)d_ws;            // N*128 floats
    float* dinv   = t + (size_t)N * 128;     // N
    int*   ofs    = (int*)(dinv + N);        // N+1
    int*   cursor = ofs + N + 1;             // N
    int*   col    = cursor + N;              // E
    int*   sums   = col + E;                 // nb_n (<= padding below)
    int*   deg    = sums + ((nb_n + 255) & ~255);  // N

    float* h   = (float*)d_out;  // layer-1 hidden lives in d_out
    float* out = (float*)d_out;

    const int nb_e = (E + 255) / 256;
    const int nb_g = (N + 31) / 32;
    const int nb_a = (int)(((long long)N * 32 + 255) / 256);

    // ---- CSR build (once; reused by both layers) ----
    hipMemsetAsync(deg, 0, (size_t)N * 4, stream);
    k_deg_edges<<<nb_e, 256, 0, stream>>>(dst, deg, E);
    k_scan1<<<nb_n, 256, 0, stream>>>(deg, dinv, ofs, sums, N);
    k_scan2<<<1, 512, 0, stream>>>(sums, nb_n);
    k_scan3<<<nb_n, 256, 0, stream>>>(ofs, cursor, sums, N, E);
    k_fill<<<nb_e, 256, 0, stream>>>(src, dst, cursor, col, E);

    // ---- layer 1 ----
    k_gemm<<<nb_g, 256, 0, stream>>>(x, W1, t, N, 0);
    k_agg_csr<<<nb_a, 256, 0, stream>>>(ofs, col, dinv, t, b1, h, N);

    // ---- layer 2 (relu fused into GEMM's X staging) ----
    k_gemm<<<nb_g, 256, 0, stream>>>(h, W2, t, N, 1);
    k_agg_csr<<<nb_a, 256, 0, stream>>>(ofs, col, dinv, t, b2, out, N);
}

// Round 3
// 579.418 us; speedup vs baseline: 9.7716x; 1.1505x over previous
//
#include <hip/hip_runtime.h>
#include <hip/hip_fp16.h>

// Two-layer cached GCN. Round 3: t stored as fp16 *pre-scaled by dinv[row]*
// so aggregation is a pure sum:  out[d] = bias + dinv[d] * sum(ts over {d} u in-nbrs).
// Halves gather footprint (51 -> 25.6 MB, L2-friendlier) and drops per-edge mults.

struct alignas(8) h4 { __half2 a, b; };

// ---------------- degree histogram ----------------
__global__ void k_deg_edges(const int* __restrict__ dst, int* __restrict__ deg, int e) {
    int i = blockIdx.x * 256 + threadIdx.x;
    if (i < e) atomicAdd(&deg[dst[i]], 1);
}

// ---------------- exclusive scan (3 kernels) + dinv ----------------
__global__ void k_scan1(const int* __restrict__ deg, float* __restrict__ dinv,
                        int* __restrict__ ofs, int* __restrict__ sums, int n) {
    __shared__ int sh[256];
    const int t = threadIdx.x;
    const int i = blockIdx.x * 256 + t;
    int v = (i < n) ? deg[i] : 0;
    if (i < n) dinv[i] = rsqrtf((float)v + 1.0f);  // +1 self-loop
    int x = v;
    sh[t] = x;
    __syncthreads();
    for (int o = 1; o < 256; o <<= 1) {
        int y = (t >= o) ? sh[t - o] : 0;
        __syncthreads();
        x += y;
        sh[t] = x;
        __syncthreads();
    }
    if (i < n) ofs[i] = x - v;
    if (t == 255) sums[blockIdx.x] = x;
}

__global__ void k_scan2(int* __restrict__ sums, int nb) {
    __shared__ int sh[512];
    const int t = threadIdx.x;
    int carry = 0;
    for (int base = 0; base < nb; base += 512) {
        int i = base + t;
        int v = (i < nb) ? sums[i] : 0;
        int x = v;
        sh[t] = x;
        __syncthreads();
        for (int o = 1; o < 512; o <<= 1) {
            int y = (t >= o) ? sh[t - o] : 0;
            __syncthreads();
            x += y;
            sh[t] = x;
            __syncthreads();
        }
        if (i < nb) sums[i] = x - v + carry;
        int tot = sh[511];
        __syncthreads();
        carry += tot;
    }
}

__global__ void k_scan3(int* __restrict__ ofs, int* __restrict__ cursor,
                        const int* __restrict__ sums, int n, int E) {
    int i = blockIdx.x * 256 + threadIdx.x;
    if (i < n) {
        int v = ofs[i] + sums[blockIdx.x];
        ofs[i] = v;
        cursor[i] = v;
    }
    if (i == 0) ofs[n] = E;
}

// ---------------- CSR fill ----------------
__global__ void k_fill(const int* __restrict__ src, const int* __restrict__ dst,
                       int* __restrict__ cursor, int* __restrict__ col, int E) {
    int e = blockIdx.x * 256 + threadIdx.x;
    if (e < E) {
        int d = dst[e];
        int pos = atomicAdd(&cursor[d], 1);
        col[pos] = src[e];
    }
}

// ---------------- GEMM: ts[N x 128](fp16) = dinv[row] * ((relu?)in[N x 128] @ W[128 x 128]) ----------------
__global__ __launch_bounds__(256, 2) void k_gemm(const float* __restrict__ in,
                                                 const float* __restrict__ W,
                                                 const float* __restrict__ dinv,
                                                 __half* __restrict__ out,
                                                 int nrows_total, int relu_in) {
    __shared__ float Wl[64 * 128];  // 32 KB
    __shared__ float Xl[32 * 128];  // 16 KB
    const int t = threadIdx.x;
    const long long row0 = (long long)blockIdx.x * 32;
    int nr = nrows_total - (int)row0;
    if (nr > 32) nr = 32;

    for (int i = t * 4; i < nr * 128; i += 256 * 4) {
        float4 v = *(const float4*)&in[row0 * 128 + i];
        if (relu_in) {
            v.x = fmaxf(v.x, 0.f); v.y = fmaxf(v.y, 0.f);
            v.z = fmaxf(v.z, 0.f); v.w = fmaxf(v.w, 0.f);
        }
        *(float4*)&Xl[i] = v;
    }

    const int c4 = t & 31;
    const int rg = t >> 5;
    float4 acc[4];
#pragma unroll
    for (int r = 0; r < 4; r++) acc[r] = make_float4(0.f, 0.f, 0.f, 0.f);

    for (int half = 0; half < 2; half++) {
        __syncthreads();
        for (int i = t * 4; i < 64 * 128; i += 256 * 4)
            *(float4*)&Wl[i] = *(const float4*)&W[half * 64 * 128 + i];
        __syncthreads();
#pragma unroll 4
        for (int k4 = 0; k4 < 16; k4++) {
            float4 wv0 = *(float4*)&Wl[(k4 * 4 + 0) * 128 + c4 * 4];
            float4 wv1 = *(float4*)&Wl[(k4 * 4 + 1) * 128 + c4 * 4];
            float4 wv2 = *(float4*)&Wl[(k4 * 4 + 2) * 128 + c4 * 4];
            float4 wv3 = *(float4*)&Wl[(k4 * 4 + 3) * 128 + c4 * 4];
#pragma unroll
            for (int r = 0; r < 4; r++) {
                float4 xv = *(float4*)&Xl[(rg + r * 8) * 128 + half * 64 + k4 * 4];
                acc[r].x += xv.x * wv0.x + xv.y * wv1.x + xv.z * wv2.x + xv.w * wv3.x;
                acc[r].y += xv.x * wv0.y + xv.y * wv1.y + xv.z * wv2.y + xv.w * wv3.y;
                acc[r].z += xv.x * wv0.z + xv.y * wv1.z + xv.z * wv2.z + xv.w * wv3.z;
                acc[r].w += xv.x * wv0.w + xv.y * wv1.w + xv.z * wv2.w + xv.w * wv3.w;
            }
        }
    }

#pragma unroll
    for (int r = 0; r < 4; r++) {
        int rr = rg + r * 8;
        if (rr < nr) {
            float dv = dinv[row0 + rr];
            h4 o;
            o.a = __float22half2_rn(make_float2(acc[r].x * dv, acc[r].y * dv));
            o.b = __float22half2_rn(make_float2(acc[r].z * dv, acc[r].w * dv));
            *(h4*)&out[(row0 + rr) * 128 + c4 * 4] = o;
        }
    }
}

// ---------------- CSR aggregation: out[d] = bias + dinv[d] * (ts[d] + sum_j ts[col[j]]) ----------------
__global__ __launch_bounds__(256) void k_agg_csr(const int* __restrict__ ofs,
                                                 const int* __restrict__ col,
                                                 const float* __restrict__ dinv,
                                                 const __half* __restrict__ ts,
                                                 const float* __restrict__ bias,
                                                 float* __restrict__ out, int n) {
    int gid = blockIdx.x * 256 + threadIdx.x;
    int row = gid >> 5;
    int lane = gid & 31;
    if (row >= n) return;

    float dd = dinv[row];
    int beg = ofs[row];
    int end = ofs[row + 1];

    // self term
    h4 sv = *(const h4*)&ts[(long long)row * 128 + lane * 4];
    float2 s0 = __half22float2(sv.a);
    float2 s1 = __half22float2(sv.b);
    float4 acc = make_float4(s0.x, s0.y, s1.x, s1.y);

    int j = beg;
    for (; j + 1 < end; j += 2) {
        int sA = col[j];
        int sB = col[j + 1];
        h4 vA = *(const h4*)&ts[(long long)sA * 128 + lane * 4];
        h4 vB = *(const h4*)&ts[(long long)sB * 128 + lane * 4];
        float2 a0 = __half22float2(vA.a), a1 = __half22float2(vA.b);
        float2 b0 = __half22float2(vB.a), b1 = __half22float2(vB.b);
        acc.x += a0.x + b0.x;
        acc.y += a0.y + b0.y;
        acc.z += a1.x + b1.x;
        acc.w += a1.y + b1.y;
    }
    if (j < end) {
        int s = col[j];
        h4 v = *(const h4*)&ts[(long long)s * 128 + lane * 4];
        float2 a0 = __half22float2(v.a), a1 = __half22float2(v.b);
        acc.x += a0.x;
        acc.y += a0.y;
        acc.z += a1.x;
        acc.w += a1.y;
    }

    float4 bv = *(const float4*)&bias[lane * 4];
    float4 o;
    o.x = bv.x + dd * acc.x;
    o.y = bv.y + dd * acc.y;
    o.z = bv.z + dd * acc.z;
    o.w = bv.w + dd * acc.w;
    *(float4*)&out[(long long)row * 128 + lane * 4] = o;
}

extern "C" void kernel_launch(void* const* d_in, const int* in_sizes, int n_in,
                              void* d_out, int out_size, void* d_ws, size_t ws_size,
                              hipStream_t stream) {
    const int N = in_sizes[0] / 128;
    const int E = in_sizes[1] / 2;
    const float* x  = (const float*)d_in[0];
    const int*   ei = (const int*)d_in[1];
    const float* W1 = (const float*)d_in[2];
    const float* b1 = (const float*)d_in[3];
    const float* W2 = (const float*)d_in[4];
    const float* b2 = (const float*)d_in[5];

    const int* src = ei;
    const int* dst = ei + E;

    const int nb_n = (N + 255) / 256;

    // workspace layout (t first, fp16 now: N*128 halves = N*256 bytes, 16B-aligned)
    __half* t     = (__half*)d_ws;                       // N*128 halves
    float* dinv   = (float*)((char*)d_ws + (size_t)N * 256);  // N floats
    int*   ofs    = (int*)(dinv + N);                    // N+1
    int*   cursor = ofs + N + 1;                         // N
    int*   col    = cursor + N;                          // E
    int*   sums   = col + E;                             // nb_n
    int*   deg    = sums + ((nb_n + 255) & ~255);        // N

    float* h   = (float*)d_out;
    float* out = (float*)d_out;

    const int nb_e = (E + 255) / 256;
    const int nb_g = (N + 31) / 32;
    const int nb_a = (int)(((long long)N * 32 + 255) / 256);

    // ---- CSR build (once; reused by both layers) ----
    hipMemsetAsync(deg, 0, (size_t)N * 4, stream);
    k_deg_edges<<<nb_e, 256, 0, stream>>>(dst, deg, E);
    k_scan1<<<nb_n, 256, 0, stream>>>(deg, dinv, ofs, sums, N);
    k_scan2<<<1, 512, 0, stream>>>(sums, nb_n);
    k_scan3<<<nb_n, 256, 0, stream>>>(ofs, cursor, sums, N, E);
    k_fill<<<nb_e, 256, 0, stream>>>(src, dst, cursor, col, E);

    // ---- layer 1 ----
    k_gemm<<<nb_g, 256, 0, stream>>>(x, W1, dinv, t, N, 0);
    k_agg_csr<<<nb_a, 256, 0, stream>>>(ofs, col, dinv, t, b1, h, N);

    // ---- layer 2 (relu fused into GEMM's X staging) ----
    k_gemm<<<nb_g, 256, 0, stream>>>(h, W2, dinv, t, N, 1);
    k_agg_csr<<<nb_a, 256, 0, stream>>>(ofs, col, dinv, t, b2, out, N);
}